// Round 3
// baseline (411.788 us; speedup 1.0000x reference)
//
#include <hip/hip_runtime.h>
#include <hip/hip_bf16.h>

#define BB 8
#define NN 2048
#define CC 128
#define FF 128
#define ALPHA 0.2f
#define CH 128         // chunks per batch
#define CLEN 16        // NN/CH
#define ROWS 8         // rows per k_out block

typedef __hip_bfloat16 bf16;

// Workspace layout (float offsets). Total ~363K floats ~= 1.45 MB.
#define OFF_FLAG 0                              // [16]
#define OFF_WA1  16                             // [C]
#define OFF_WA2  (OFF_WA1 + CC)                 // [C]
#define OFF_E1   (OFF_WA2 + CC)                 // [B*N]
#define OFF_E2   (OFF_E1 + BB*NN)               // [B*N]
#define OFF_E2S  (OFF_E2 + BB*NN)               // [B*N] sorted ascending
#define OFF_SIDX (OFF_E2S + BB*NN)              // [B*N] (int) permutation
#define OFF_Z1   (OFF_SIDX + BB*NN)             // [B*(N+1)] excl prefix of exp(e2s)
#define OFF_Z2   (OFF_Z1 + BB*(NN+1))           // [B*(N+1)] excl prefix of exp(.2*e2s)
#define OFF_G1   (OFF_Z2 + BB*(NN+1))           // [B*(CH+1)*C] chunk excl prefixes (C-space) + total
#define OFF_G2   (OFF_G1 + BB*(CH+1)*CC)        // [B*(CH+1)*C]
#define WS_FLOATS (OFF_G2 + BB*(CH+1)*CC)       // = 362,784 floats = 1.45 MB

// ---------------- dtype helpers ----------------
__device__ __forceinline__ float ld1(const void* p, int i, int f32) {
    if (f32) return ((const float*)p)[i];
    return __bfloat162float(((const bf16*)p)[i]);
}
__device__ __forceinline__ float2 ld2(const void* p, int pair, int f32) {
    if (f32) return ((const float2*)p)[pair];
    __hip_bfloat162 v = ((const __hip_bfloat162*)p)[pair];
    return make_float2(__bfloat162float(v.x), __bfloat162float(v.y));
}

// ---------------- K0: detect input dtype (fp32 low-half words look huge as bf16) ----
__global__ __launch_bounds__(256) void k_flag(const void* __restrict__ text,
                                              int* __restrict__ flag) {
    __shared__ int cnt;
    if (threadIdx.x == 0) cnt = 0;
    __syncthreads();
    const ushort2* p = (const ushort2*)text;   // 4 KB probe, safe either way
    int local = 0;
    for (int i = threadIdx.x; i < 1024; i += 256) {
        ushort2 v = p[i];
        float f = __uint_as_float(((unsigned)v.x) << 16);
        if (!(fabsf(f) <= 100.f)) local++;
    }
    atomicAdd(&cnt, local);
    __syncthreads();
    if (threadIdx.x == 0) flag[0] = (cnt >= 64) ? 1 : 0;
}

// ---------------- K1: Wa1 = W@a1, Wa2 = W@a2 (C-vectors) ----------------
__global__ __launch_bounds__(128) void k_wa(const void* __restrict__ W,
                                            const void* __restrict__ a,
                                            float* __restrict__ wa1,
                                            float* __restrict__ wa2,
                                            const int* __restrict__ flag) {
    const int f32 = *flag;
    const int c = threadIdx.x;
    float s1 = 0.f, s2 = 0.f;
    for (int f = 0; f < FF; ++f) {
        float w = ld1(W, c * FF + f, f32);
        s1 += w * ld1(a, f, f32);
        s2 += w * ld1(a, FF + f, f32);
    }
    wa1[c] = s1;
    wa2[c] = s2;
}

// ---------------- K2: e1/e2 per row (wave per row) ----------------
__global__ __launch_bounds__(256) void k_e(const void* __restrict__ text,
                                           const float* __restrict__ wa1,
                                           const float* __restrict__ wa2,
                                           float* __restrict__ e1,
                                           float* __restrict__ e2,
                                           const int* __restrict__ flag) {
    const int f32 = *flag;
    const int wave = threadIdx.x >> 6;
    const int lane = threadIdx.x & 63;
    const int row = blockIdx.x * 4 + wave;
    float2 tv = ld2(text, row * (CC / 2) + lane, f32);
    float s1 = tv.x * wa1[2 * lane] + tv.y * wa1[2 * lane + 1];
    float s2 = tv.x * wa2[2 * lane] + tv.y * wa2[2 * lane + 1];
#pragma unroll
    for (int off = 32; off > 0; off >>= 1) {
        s1 += __shfl_down(s1, off, 64);
        s2 += __shfl_down(s2, off, 64);
    }
    if (lane == 0) { e1[row] = s1; e2[row] = s2; }
}

// ---------------- K3: per-batch bitonic sort of e2 + scalar exp scans ----------------
__global__ __launch_bounds__(1024) void k_sort(const float* __restrict__ e2,
                                               float* __restrict__ e2s,
                                               int* __restrict__ sidx,
                                               float* __restrict__ z1,
                                               float* __restrict__ z2) {
    __shared__ float vals[NN];
    __shared__ int   idxs[NN];
    __shared__ float bufA[NN];
    __shared__ float bufB[NN];
    const int b = blockIdx.x;
    const int t = threadIdx.x;

    for (int i = t; i < NN; i += 1024) { vals[i] = e2[b * NN + i]; idxs[i] = i; }
    __syncthreads();

    for (int size = 2; size <= NN; size <<= 1) {
        for (int stride = size >> 1; stride > 0; stride >>= 1) {
            int i = ((t & ~(stride - 1)) << 1) | (t & (stride - 1));
            int j = i | stride;
            bool up = ((i & size) == 0);
            float vi = vals[i], vj = vals[j];
            bool sw = up ? (vi > vj) : (vi < vj);
            if (sw) {
                vals[i] = vj; vals[j] = vi;
                int ti = idxs[i]; idxs[i] = idxs[j]; idxs[j] = ti;
            }
            __syncthreads();
        }
    }

    for (int i = t; i < NN; i += 1024) {
        e2s[b * NN + i] = vals[i];
        sidx[b * NN + i] = idxs[i];
    }

    for (int pass = 0; pass < 2; ++pass) {
        float scale = (pass == 0) ? 1.0f : ALPHA;
        float* zout = (pass == 0) ? z1 : z2;
        __syncthreads();
        for (int i = t; i < NN; i += 1024) bufA[i] = expf(scale * vals[i]);
        __syncthreads();
        float* pA = bufA; float* pB = bufB;
        for (int off = 1; off < NN; off <<= 1) {
            for (int i = t; i < NN; i += 1024)
                pB[i] = pA[i] + ((i >= off) ? pA[i - off] : 0.f);
            __syncthreads();
            float* tmp = pA; pA = pB; pB = tmp;
        }
        if (t == 0) zout[b * (NN + 1)] = 0.f;
        for (int i = t; i < NN; i += 1024) zout[b * (NN + 1) + 1 + i] = pA[i];
    }
}

// ---------------- K4: per-chunk weighted TEXT sums (C-space) ----------------
__global__ __launch_bounds__(128) void k_chunks(const void* __restrict__ text,
                                                const float* __restrict__ e2s,
                                                const int* __restrict__ sidx,
                                                float* __restrict__ G1,
                                                float* __restrict__ G2,
                                                const int* __restrict__ flag) {
    const int f32 = *flag;
    const int b = blockIdx.x / CH, ch = blockIdx.x % CH;
    const int c = threadIdx.x;
    float r1 = 0.f, r2 = 0.f;
#pragma unroll
    for (int kk = 0; kk < CLEN; ++kk) {
        int k = ch * CLEN + kk;
        float v = e2s[b * NN + k];
        int j = sidx[b * NN + k];
        float x = ld1(text, (b * NN + j) * CC + c, f32);
        r1 += expf(v) * x;
        r2 += expf(ALPHA * v) * x;
    }
    G1[(b * (CH + 1) + ch) * CC + c] = r1;
    G2[(b * (CH + 1) + ch) * CC + c] = r2;
}

// ---------------- K5: exclusive scan of chunk sums (+ total at CH) ----------------
__global__ __launch_bounds__(256) void k_scanchunks(float* __restrict__ G1,
                                                    float* __restrict__ G2) {
    const int tid = blockIdx.x * 256 + threadIdx.x;   // 0..B*C-1
    const int b = tid / CC, c = tid % CC;
    float* P1 = G1 + (size_t)(b * (CH + 1)) * CC + c;
    float* P2 = G2 + (size_t)(b * (CH + 1)) * CC + c;
    float r1 = 0.f, r2 = 0.f;
    for (int ch = 0; ch < CH; ++ch) {
        float t1 = P1[ch * CC], t2 = P2[ch * CC];
        P1[ch * CC] = r1; r1 += t1;
        P2[ch * CC] = r2; r2 += t2;
    }
    P1[CH * CC] = r1;   // totals
    P2[CH * CC] = r2;
}

// ---------------- K6: per-row combine in C-space, fused @W, elu, store ----------------
__global__ __launch_bounds__(128) void k_out(const void* __restrict__ text,
                                             const void* __restrict__ W,
                                             const float* __restrict__ e1,
                                             const float* __restrict__ e2s,
                                             const int* __restrict__ sidx,
                                             const float* __restrict__ z1,
                                             const float* __restrict__ z2,
                                             const float* __restrict__ G1,
                                             const float* __restrict__ G2,
                                             void* __restrict__ out,
                                             const int* __restrict__ flag) {
    const int f32 = *flag;
    const int b = blockIdx.x / (NN / ROWS);
    const int r0 = (blockIdx.x % (NN / ROWS)) * ROWS;
    const int c = threadIdx.x;                 // doubles as f for the output dot

    __shared__ float Wl[CC * FF];              // 64 KB fp32 staged W
    __shared__ float ul[ROWS * CC];            // 4 KB combined C-vectors
#pragma unroll
    for (int t = 0; t < 64; ++t) {             // 8192 pairs, coalesced
        int p = c + t * 128;
        float2 v = ld2(W, p, f32);
        Wl[2 * p] = v.x;
        Wl[2 * p + 1] = v.y;
    }

    const float S1 = G1[(b * (CH + 1) + CH) * CC + c];   // per-c totals
    const float* e2sb = e2s + b * NN;

#pragma unroll
    for (int rr = 0; rr < ROWS; ++rr) {
        const int row = b * NN + r0 + rr;
        float ev = e1[row];
        float w1 = expf(ev), w2 = expf(ALPHA * ev);
        float thr = -ev;
        int lo = 0, hi = NN;
        while (lo < hi) {                      // k = #{ j : e2s[j] <= thr }
            int mid = (lo + hi) >> 1;
            if (e2sb[mid] <= thr) lo = mid + 1; else hi = mid;
        }
        const int k = lo;
        const int c0 = k / CLEN;
        float P1 = G1[(b * (CH + 1) + c0) * CC + c];
        float P2 = G2[(b * (CH + 1) + c0) * CC + c];
        for (int t = c0 * CLEN; t < k; ++t) {  // <= CLEN-1 = 15 terms
            float v = e2sb[t];
            int j = sidx[b * NN + t];
            float x = ld1(text, (b * NN + j) * CC + c, f32);
            P1 += expf(v) * x;
            P2 += expf(ALPHA * v) * x;
        }
        float den = w1 * (z1[b * (NN + 1) + NN] - z1[b * (NN + 1) + k])
                  + w2 * z2[b * (NN + 1) + k];
        den = fmaxf(den, 1e-30f);
        float inv = 1.f / den;
        float tc = ld1(text, row * CC + c, f32);
        ul[rr * CC + c] = (w1 * (S1 - P1) + w2 * P2) * inv + ALPHA * tc;
    }
    __syncthreads();

    float xacc[ROWS];
#pragma unroll
    for (int rr = 0; rr < ROWS; ++rr) xacc[rr] = 0.f;
    for (int cc4 = 0; cc4 < CC; cc4 += 4) {
        float w0 = Wl[(cc4 + 0) * FF + c];
        float w1_ = Wl[(cc4 + 1) * FF + c];
        float w2_ = Wl[(cc4 + 2) * FF + c];
        float w3_ = Wl[(cc4 + 3) * FF + c];
#pragma unroll
        for (int rr = 0; rr < ROWS; ++rr) {
            float4 uv = *(const float4*)&ul[rr * CC + cc4];
            xacc[rr] += uv.x * w0 + uv.y * w1_ + uv.z * w2_ + uv.w * w3_;
        }
    }
#pragma unroll
    for (int rr = 0; rr < ROWS; ++rr) {
        float x = xacc[rr];
        float y = x > 0.f ? x : expm1f(x);
        int row = b * NN + r0 + rr;
        if (f32) ((float*)out)[row * FF + c] = y;
        else     ((bf16*)out)[row * FF + c] = __float2bfloat16(y);
    }
}

extern "C" void kernel_launch(void* const* d_in, const int* in_sizes, int n_in,
                              void* d_out, int out_size, void* d_ws, size_t ws_size,
                              hipStream_t stream) {
    // Identify inputs by element count (robust to adj being pruned):
    const void* text = d_in[0];
    const void* Wp   = (n_in >= 4) ? d_in[2] : d_in[1];
    const void* ap   = (n_in >= 4) ? d_in[3] : d_in[2];
    for (int i = 0; i < n_in; ++i) {
        int s = in_sizes[i];
        if (s == BB * NN * CC)      text = d_in[i];
        else if (s == CC * FF)      Wp = d_in[i];
        else if (s == 2 * FF)       ap = d_in[i];
    }

    float* w = (float*)d_ws;
    int*   flagp = (int*)(w + OFF_FLAG);
    float* wa1  = w + OFF_WA1;
    float* wa2  = w + OFF_WA2;
    float* e1   = w + OFF_E1;
    float* e2   = w + OFF_E2;
    float* e2s  = w + OFF_E2S;
    int*   sidx = (int*)(w + OFF_SIDX);
    float* z1   = w + OFF_Z1;
    float* z2   = w + OFF_Z2;
    float* G1   = w + OFF_G1;
    float* G2   = w + OFF_G2;

    k_flag<<<1, 256, 0, stream>>>(text, flagp);
    k_wa<<<1, 128, 0, stream>>>(Wp, ap, wa1, wa2, flagp);
    k_e<<<BB * NN / 4, 256, 0, stream>>>(text, wa1, wa2, e1, e2, flagp);
    k_sort<<<BB, 1024, 0, stream>>>(e2, e2s, sidx, z1, z2);
    k_chunks<<<BB * CH, 128, 0, stream>>>(text, e2s, sidx, G1, G2, flagp);
    k_scanchunks<<<(BB * CC) / 256, 256, 0, stream>>>(G1, G2);
    k_out<<<BB * NN / ROWS, 128, 0, stream>>>(text, Wp, e1, e2s, sidx, z1, z2,
                                              G1, G2, d_out, flagp);
}

// Round 4
// 319.144 us; speedup vs baseline: 1.2903x; 1.2903x over previous
//
#include <hip/hip_runtime.h>
#include <hip/hip_bf16.h>

#define BB 8
#define NN 2048
#define CC 128
#define FF 128
#define ALPHA 0.2f
#define ROWS 16        // rows per k_out block
#define WTPAD 136      // padded LDS row stride in ushorts (272 B): breaks bank conflicts

typedef __hip_bfloat16 bf16;
typedef __attribute__((ext_vector_type(8))) short short8;   // 8 bf16 MFMA operand
typedef __attribute__((ext_vector_type(4))) float f32x4;    // MFMA accumulator

// ---------------- dtype helpers ----------------
__device__ __forceinline__ float ld1(const void* p, int i, int f32) {
    if (f32) return ((const float*)p)[i];
    return __bfloat162float(((const bf16*)p)[i]);
}
__device__ __forceinline__ float2 ld2(const void* p, int pair, int f32) {
    if (f32) return ((const float2*)p)[pair];
    __hip_bfloat162 v = ((const __hip_bfloat162*)p)[pair];
    return make_float2(__bfloat162float(v.x), __bfloat162float(v.y));
}

// ---------------- K_prep: flag + wa + WT(bf16, f-major) ----------------
__global__ __launch_bounds__(256) void k_prep(const void* __restrict__ text,
                                              const void* __restrict__ W,
                                              const void* __restrict__ a,
                                              int* __restrict__ flag,
                                              float* __restrict__ wa1,
                                              float* __restrict__ wa2,
                                              ushort* __restrict__ WT) {
    __shared__ int cnt;
    __shared__ float aL[2 * FF];
    const int t = threadIdx.x;
    if (t == 0) cnt = 0;
    __syncthreads();
    // dtype probe: fp32 low-half words decode as huge bf16 values
    const ushort2* p = (const ushort2*)text;
    int local = 0;
    for (int i = t; i < 1024; i += 256) {
        ushort2 v = p[i];
        float f = __uint_as_float(((unsigned)v.x) << 16);
        if (!(fabsf(f) <= 100.f)) local++;
    }
    atomicAdd(&cnt, local);
    __syncthreads();
    const int f32 = (cnt >= 64) ? 1 : 0;

    if (blockIdx.x == 0) {
        if (t == 0) flag[0] = f32;
        aL[t] = ld1(a, t, f32);          // t < 256 = 2F
        __syncthreads();
        if (t < CC) {
            float s1 = 0.f, s2 = 0.f;
            for (int f = 0; f < FF; f += 4) {
                float w0 = ld1(W, t * FF + f, f32);
                float w1 = ld1(W, t * FF + f + 1, f32);
                float w2 = ld1(W, t * FF + f + 2, f32);
                float w3 = ld1(W, t * FF + f + 3, f32);
                s1 += w0 * aL[f] + w1 * aL[f + 1] + w2 * aL[f + 2] + w3 * aL[f + 3];
                s2 += w0 * aL[FF + f] + w1 * aL[FF + f + 1] + w2 * aL[FF + f + 2] + w3 * aL[FF + f + 3];
            }
            wa1[t] = s1; wa2[t] = s2;
        }
    } else {
        // WT[f*CC+cc] = bf16(W[cc*FF+f]); coalesced reads, scattered 2B writes
        const int base = (blockIdx.x - 1) * 2048;
        for (int i = 0; i < 8; ++i) {
            int idx = base + i * 256 + t;          // idx = cc*FF + f
            int cc = idx >> 7, f = idx & 127;
            float v = ld1(W, idx, f32);
            bf16 b = __float2bfloat16(v);
            WT[f * CC + cc] = *(const ushort*)&b;
        }
    }
}

// ---------------- K_e: e1/e2 per row (wave per row) ----------------
__global__ __launch_bounds__(256) void k_e(const void* __restrict__ text,
                                           const float* __restrict__ wa1,
                                           const float* __restrict__ wa2,
                                           float* __restrict__ e1,
                                           float* __restrict__ e2,
                                           const int* __restrict__ flag) {
    const int f32 = *flag;
    const int wave = threadIdx.x >> 6;
    const int lane = threadIdx.x & 63;
    const int row = blockIdx.x * 4 + wave;
    float2 tv = ld2(text, row * (CC / 2) + lane, f32);
    float s1 = tv.x * wa1[2 * lane] + tv.y * wa1[2 * lane + 1];
    float s2 = tv.x * wa2[2 * lane] + tv.y * wa2[2 * lane + 1];
#pragma unroll
    for (int off = 32; off > 0; off >>= 1) {
        s1 += __shfl_down(s1, off, 64);
        s2 += __shfl_down(s2, off, 64);
    }
    if (lane == 0) { e1[row] = s1; e2[row] = s2; }
}

// ---------------- K_sort: bitonic sort + wave-shuffle scans ----------------
__global__ __launch_bounds__(1024) void k_sort(const float* __restrict__ e2,
                                               float* __restrict__ e2s,
                                               int* __restrict__ sidx,
                                               float* __restrict__ z1,
                                               float* __restrict__ z2) {
    __shared__ float vals[NN];
    __shared__ int   idxs[NN];
    __shared__ float2 wtot[16];
    __shared__ float2 woff[16];
    const int b = blockIdx.x;
    const int t = threadIdx.x;

    for (int i = t; i < NN; i += 1024) { vals[i] = e2[b * NN + i]; idxs[i] = i; }
    __syncthreads();

    for (int size = 2; size <= NN; size <<= 1) {
        for (int stride = size >> 1; stride > 0; stride >>= 1) {
            int i = ((t & ~(stride - 1)) << 1) | (t & (stride - 1));
            int j = i | stride;
            bool up = ((i & size) == 0);
            float vi = vals[i], vj = vals[j];
            bool sw = up ? (vi > vj) : (vi < vj);
            if (sw) {
                vals[i] = vj; vals[j] = vi;
                int ti = idxs[i]; idxs[i] = idxs[j]; idxs[j] = ti;
            }
            __syncthreads();
        }
    }

    for (int i = t; i < NN; i += 1024) {
        e2s[b * NN + i] = vals[i];
        sidx[b * NN + i] = idxs[i];
    }

    // dual inclusive scan (exp(v), exp(.2v)) via wave shuffles: 2 barriers
    float v0 = vals[2 * t], v1 = vals[2 * t + 1];
    float x0a = expf(v0), x0b = expf(ALPHA * v0);
    float x1a = expf(v1), x1b = expf(ALPHA * v1);
    float pa = x0a + x1a, pb = x0b + x1b;
    float sa = pa, sb = pb;
    const int lane = t & 63, wid = t >> 6;
#pragma unroll
    for (int off = 1; off < 64; off <<= 1) {
        float ya = __shfl_up(sa, off, 64);
        float yb = __shfl_up(sb, off, 64);
        if (lane >= off) { sa += ya; sb += yb; }
    }
    if (lane == 63) wtot[wid] = make_float2(sa, sb);
    __syncthreads();
    if (t == 0) {
        float ra = 0.f, rb = 0.f;
        for (int w2 = 0; w2 < 16; ++w2) {
            float2 tt = wtot[w2];
            woff[w2] = make_float2(ra, rb);
            ra += tt.x; rb += tt.y;
        }
    }
    __syncthreads();
    float2 o = woff[wid];
    float pre_a = o.x + sa - pa, pre_b = o.y + sb - pb;
    float* Z1 = z1 + b * (NN + 1);
    float* Z2 = z2 + b * (NN + 1);
    if (t == 0) { Z1[0] = 0.f; Z2[0] = 0.f; }
    Z1[2 * t + 1] = pre_a + x0a;  Z2[2 * t + 1] = pre_b + x0b;
    Z1[2 * t + 2] = pre_a + pa;   Z2[2 * t + 2] = pre_b + pb;
}

// ---------------- K_chunks: per-chunk weighted text sums (C-space) ----------------
__global__ __launch_bounds__(128) void k_chunks(const void* __restrict__ text,
                                                const float* __restrict__ e2s,
                                                const int* __restrict__ sidx,
                                                float* __restrict__ G1,
                                                float* __restrict__ G2,
                                                const int* __restrict__ flag,
                                                int CH_, int CLEN_) {
    const int f32 = *flag;
    const int b = blockIdx.x / CH_, ch = blockIdx.x % CH_;
    const int c = threadIdx.x;
    float r1 = 0.f, r2 = 0.f;
    const int k0 = ch * CLEN_;
    for (int kk = 0; kk < CLEN_; ++kk) {
        int k = k0 + kk;
        float v = e2s[b * NN + k];
        int j = sidx[b * NN + k];
        float x = ld1(text, (b * NN + j) * CC + c, f32);
        r1 += expf(v) * x;
        r2 += expf(ALPHA * v) * x;
    }
    G1[(b * (CH_ + 1) + ch) * CC + c] = r1;
    G2[(b * (CH_ + 1) + ch) * CC + c] = r2;
}

// ---------------- K_mid: chunk scan (blocks 0..3) + rowinfo (blocks 4..67) ----------
__global__ __launch_bounds__(256) void k_mid(float* __restrict__ G1,
                                             float* __restrict__ G2,
                                             const float* __restrict__ e1,
                                             const float* __restrict__ e2s,
                                             const float* __restrict__ z1,
                                             const float* __restrict__ z2,
                                             float4* __restrict__ rowinfo,
                                             int CH_) {
    if (blockIdx.x < 4) {
        const int tid = blockIdx.x * 256 + threadIdx.x;   // 0..B*C-1
        const int b = tid / CC, c = tid % CC;
        float* P1 = G1 + (size_t)(b * (CH_ + 1)) * CC + c;
        float* P2 = G2 + (size_t)(b * (CH_ + 1)) * CC + c;
        float r1 = 0.f, r2 = 0.f;
        for (int ch = 0; ch < CH_; ++ch) {
            float t1 = P1[ch * CC], t2 = P2[ch * CC];
            P1[ch * CC] = r1; r1 += t1;
            P2[ch * CC] = r2; r2 += t2;
        }
        P1[CH_ * CC] = r1;   // totals
        P2[CH_ * CC] = r2;
    } else {
        const int row = (blockIdx.x - 4) * 256 + threadIdx.x;  // 0..16383
        const int b = row >> 11;
        float ev = e1[row];
        float w1 = expf(ev), w2 = expf(ALPHA * ev);
        float thr = -ev;
        const float* e2sb = e2s + b * NN;
        int lo = 0, hi = NN;
        while (lo < hi) {                  // k = #{ j : e2s[j] <= thr }
            int mid = (lo + hi) >> 1;
            if (e2sb[mid] <= thr) lo = mid + 1; else hi = mid;
        }
        float den = w1 * (z1[b * (NN + 1) + NN] - z1[b * (NN + 1) + lo])
                  + w2 * z2[b * (NN + 1) + lo];
        den = fmaxf(den, 1e-30f);
        rowinfo[row] = make_float4(__int_as_float(lo), w1, w2, 1.f / den);
    }
}

// ---------------- K_out: combine (phase 1) + MFMA @W (phase 2) + elu store -------
__global__ __launch_bounds__(256) void k_out(const void* __restrict__ text,
                                             const ushort* __restrict__ WT,
                                             const float* __restrict__ G1,
                                             const float* __restrict__ G2,
                                             const float4* __restrict__ rowinfo,
                                             const float* __restrict__ e2s,
                                             const int* __restrict__ sidx,
                                             void* __restrict__ out,
                                             const int* __restrict__ flag,
                                             int CH_, int CLEN_, int CLEN_SHIFT) {
    __shared__ ushort WTl[FF * WTPAD];     // 34816 B, bf16 W^T padded
    __shared__ ushort ul[ROWS * WTPAD];    // 4352 B, bf16 u-tile padded
    __shared__ float4 ri[ROWS];
    const int f32 = *flag;
    const int t = threadIdx.x;
    const int b = blockIdx.x / (NN / ROWS);
    const int r0 = (blockIdx.x % (NN / ROWS)) * ROWS;

    // stage W^T: 2048 uint4 coalesced
    {
        const uint4* src = (const uint4*)WT;
#pragma unroll
        for (int i = 0; i < 8; ++i) {
            int idx = i * 256 + t;            // f = idx>>4, 16B-chunk = idx&15
            uint4 v = src[idx];
            int f = idx >> 4, cb = idx & 15;
            *(uint4*)&WTl[f * WTPAD + cb * 8] = v;
        }
    }
    if (t < ROWS) ri[t] = rowinfo[b * NN + r0 + t];
    __syncthreads();

    // phase 1: u[rr][c] = (w1*(S1-P1) + w2*P2)*inv + alpha*text  -> bf16 in LDS
    {
        const int c = t & 127;
        const int g = t >> 7;                 // 0..1 -> rows g*8..g*8+7
        const float S1 = G1[(b * (CH_ + 1) + CH_) * CC + c];
        const float* e2sb = e2s + b * NN;
        const int* sb = sidx + b * NN;
#pragma unroll
        for (int q = 0; q < 8; ++q) {
            const int rr = g * 8 + q;
            float4 info = ri[rr];
            const int k = __float_as_int(info.x);
            const float w1 = info.y, w2 = info.z, inv = info.w;
            const int c0 = k >> CLEN_SHIFT;
            float P1 = G1[(b * (CH_ + 1) + c0) * CC + c];
            float P2 = G2[(b * (CH_ + 1) + c0) * CC + c];
            for (int t2 = c0 << CLEN_SHIFT; t2 < k; ++t2) {
                float v = e2sb[t2];
                int j = sb[t2];
                float x = ld1(text, (b * NN + j) * CC + c, f32);
                P1 += expf(v) * x;
                P2 += expf(ALPHA * v) * x;
            }
            float tc = ld1(text, (b * NN + r0 + rr) * CC + c, f32);
            float u = (w1 * (S1 - P1) + w2 * P2) * inv + ALPHA * tc;
            bf16 ub = __float2bfloat16(u);
            ul[rr * WTPAD + c] = *(const ushort*)&ub;
        }
    }
    __syncthreads();

    // phase 2: out[16 x 128] = elu(u @ W) via MFMA 16x16x32 bf16
    {
        const int wv = t >> 6;                // wave 0..3 -> f-tiles 2wv, 2wv+1
        const int lane = t & 63;
        const int m = lane & 15;
        const int quad = lane >> 4;
        f32x4 acc0 = {0.f, 0.f, 0.f, 0.f};
        f32x4 acc1 = {0.f, 0.f, 0.f, 0.f};
        const int f0 = (wv * 2 + 0) * 16 + m;
        const int f1 = (wv * 2 + 1) * 16 + m;
#pragma unroll
        for (int kt = 0; kt < 4; ++kt) {
            const int ko = kt * 32 + quad * 8;
            short8 afrag = *(const short8*)&ul[m * WTPAD + ko];
            short8 bf0 = *(const short8*)&WTl[f0 * WTPAD + ko];
            short8 bf1 = *(const short8*)&WTl[f1 * WTPAD + ko];
            acc0 = __builtin_amdgcn_mfma_f32_16x16x32_bf16(afrag, bf0, acc0, 0, 0, 0);
            acc1 = __builtin_amdgcn_mfma_f32_16x16x32_bf16(afrag, bf1, acc1, 0, 0, 0);
        }
        // C/D: col = lane&15 (f within tile), row = quad*4+reg (u-row)
#pragma unroll
        for (int ft = 0; ft < 2; ++ft) {
            f32x4 acc = ft ? acc1 : acc0;
            const int f = (wv * 2 + ft) * 16 + m;
#pragma unroll
            for (int reg = 0; reg < 4; ++reg) {
                const int urow = quad * 4 + reg;
                float x = acc[reg];
                float y = x > 0.f ? x : expm1f(x);
                const int orow = b * NN + r0 + urow;
                if (f32) ((float*)out)[orow * FF + f] = y;
                else     ((bf16*)out)[orow * FF + f] = __float2bfloat16(y);
            }
        }
    }
}

extern "C" void kernel_launch(void* const* d_in, const int* in_sizes, int n_in,
                              void* d_out, int out_size, void* d_ws, size_t ws_size,
                              hipStream_t stream) {
    // Identify inputs by element count (robust to adj being pruned)
    const void* text = d_in[0];
    const void* Wp   = (n_in >= 4) ? d_in[2] : d_in[1];
    const void* ap   = (n_in >= 4) ? d_in[3] : d_in[2];
    for (int i = 0; i < n_in; ++i) {
        int s = in_sizes[i];
        if (s == BB * NN * CC)      text = d_in[i];
        else if (s == CC * FF)      Wp = d_in[i];
        else if (s == 2 * FF)       ap = d_in[i];
    }

    // Choose CH to provably fit ws_size (Round 3 proved >= 1.45 MB available).
    const size_t fixed_floats = 16 + 128 + 128 + 8192 /*WT*/ + 4 * (size_t)(BB * NN)
                              + 2 * (size_t)(BB * (NN + 1)) + 4 * (size_t)(BB * NN) /*rowinfo*/;
    int CH_ = 256;
    while (CH_ > 32) {
        size_t need = (fixed_floats + 2 * (size_t)BB * (CH_ + 1) * CC) * 4;
        if (need <= ws_size) break;
        CH_ >>= 1;
    }
    const int CLEN_ = NN / CH_;
    int cs = 0; while ((1 << cs) < CLEN_) cs++;   // log2(CLEN_)

    float* w = (float*)d_ws;
    size_t off = 0;
    int*    flagp  = (int*)(w + off);      off += 16;
    float*  wa1    = w + off;              off += 128;
    float*  wa2    = w + off;              off += 128;
    ushort* WT     = (ushort*)(w + off);   off += 8192;            // 16K bf16, 16B-aligned
    float*  e1     = w + off;              off += BB * NN;
    float*  e2     = w + off;              off += BB * NN;
    float*  e2s    = w + off;              off += BB * NN;
    int*    sidx   = (int*)(w + off);      off += BB * NN;
    float*  z1     = w + off;              off += BB * (NN + 1);
    float*  z2     = w + off;              off += BB * (NN + 1);
    float4* rowinfo= (float4*)(w + ((off + 3) & ~(size_t)3));
    off = ((off + 3) & ~(size_t)3) + 4 * BB * NN;
    float*  G1     = w + off;              off += (size_t)BB * (CH_ + 1) * CC;
    float*  G2     = w + off;

    k_prep<<<9, 256, 0, stream>>>(text, Wp, ap, flagp, wa1, wa2, WT);
    k_e<<<BB * NN / 4, 256, 0, stream>>>(text, wa1, wa2, e1, e2, flagp);
    k_sort<<<BB, 1024, 0, stream>>>(e2, e2s, sidx, z1, z2);
    k_chunks<<<BB * CH_, 128, 0, stream>>>(text, e2s, sidx, G1, G2, flagp, CH_, CLEN_);
    k_mid<<<4 + BB * NN / 256, 256, 0, stream>>>(G1, G2, e1, e2s, z1, z2, rowinfo, CH_);
    k_out<<<BB * NN / ROWS, 256, 0, stream>>>(text, WT, G1, G2, rowinfo, e2s, sidx,
                                              d_out, flagp, CH_, CLEN_, cs);
}

// Round 5
// 244.037 us; speedup vs baseline: 1.6874x; 1.3078x over previous
//
#include <hip/hip_runtime.h>
#include <hip/hip_bf16.h>

#define BB 8
#define NN 2048
#define CC 128
#define FF 128
#define ALPHA 0.2f
#define ROWS 16        // rows per k_out block
#define WTPAD 136      // padded LDS row stride in ushorts (272 B)
#define CHN 256        // chunks per batch
#define CLEN 8         // NN/CHN
#define CSH 3          // log2(CLEN)

typedef __hip_bfloat16 bf16;
typedef __attribute__((ext_vector_type(8))) short short8;   // 8 bf16 MFMA operand
typedef __attribute__((ext_vector_type(4))) float f32x4;    // MFMA accumulator

// ---------------- dtype helpers ----------------
__device__ __forceinline__ float ld1(const void* p, int i, int f32) {
    if (f32) return ((const float*)p)[i];
    return __bfloat162float(((const bf16*)p)[i]);
}
__device__ __forceinline__ float2 ld2(const void* p, int pair, int f32) {
    if (f32) return ((const float2*)p)[pair];
    __hip_bfloat162 v = ((const __hip_bfloat162*)p)[pair];
    return make_float2(__bfloat162float(v.x), __bfloat162float(v.y));
}

// ---------------- K_prep: flag + wa + WT(bf16, f-major) ----------------
__global__ __launch_bounds__(256) void k_prep(const void* __restrict__ text,
                                              const void* __restrict__ W,
                                              const void* __restrict__ a,
                                              int* __restrict__ flag,
                                              float* __restrict__ wa1,
                                              float* __restrict__ wa2,
                                              ushort* __restrict__ WT) {
    __shared__ int cnt;
    __shared__ float aL[2 * FF];
    const int t = threadIdx.x;
    if (t == 0) cnt = 0;
    __syncthreads();
    // dtype probe: fp32 low-half words decode as huge bf16 values
    const ushort2* p = (const ushort2*)text;
    int local = 0;
    for (int i = t; i < 1024; i += 256) {
        ushort2 v = p[i];
        float f = __uint_as_float(((unsigned)v.x) << 16);
        if (!(fabsf(f) <= 100.f)) local++;
    }
    atomicAdd(&cnt, local);
    __syncthreads();
    const int f32 = (cnt >= 64) ? 1 : 0;

    if (blockIdx.x == 0) {
        if (t == 0) flag[0] = f32;
        aL[t] = ld1(a, t, f32);          // t < 256 = 2F
        __syncthreads();
        if (t < CC) {
            float s1 = 0.f, s2 = 0.f;
            for (int f = 0; f < FF; f += 4) {
                float w0 = ld1(W, t * FF + f, f32);
                float w1 = ld1(W, t * FF + f + 1, f32);
                float w2 = ld1(W, t * FF + f + 2, f32);
                float w3 = ld1(W, t * FF + f + 3, f32);
                s1 += w0 * aL[f] + w1 * aL[f + 1] + w2 * aL[f + 2] + w3 * aL[f + 3];
                s2 += w0 * aL[FF + f] + w1 * aL[FF + f + 1] + w2 * aL[FF + f + 2] + w3 * aL[FF + f + 3];
            }
            wa1[t] = s1; wa2[t] = s2;
        }
    } else {
        // WT[f*CC+cc] = bf16(W[cc*FF+f])
        const int base = (blockIdx.x - 1) * 2048;
        for (int i = 0; i < 8; ++i) {
            int idx = base + i * 256 + t;          // idx = cc*FF + f
            int cc = idx >> 7, f = idx & 127;
            float v = ld1(W, idx, f32);
            bf16 b = __float2bfloat16(v);
            WT[f * CC + cc] = *(const ushort*)&b;
        }
    }
}

// ---------------- K_e: e1/e2 per row (wave per row) ----------------
__global__ __launch_bounds__(256) void k_e(const void* __restrict__ text,
                                           const float* __restrict__ wa1,
                                           const float* __restrict__ wa2,
                                           float* __restrict__ e1,
                                           float* __restrict__ e2,
                                           const int* __restrict__ flag) {
    const int f32 = *flag;
    const int wave = threadIdx.x >> 6;
    const int lane = threadIdx.x & 63;
    const int row = blockIdx.x * 4 + wave;
    float2 tv = ld2(text, row * (CC / 2) + lane, f32);
    float s1 = tv.x * wa1[2 * lane] + tv.y * wa1[2 * lane + 1];
    float s2 = tv.x * wa2[2 * lane] + tv.y * wa2[2 * lane + 1];
#pragma unroll
    for (int off = 32; off > 0; off >>= 1) {
        s1 += __shfl_down(s1, off, 64);
        s2 += __shfl_down(s2, off, 64);
    }
    if (lane == 0) { e1[row] = s1; e2[row] = s2; }
}

// ---------------- K_sort: bitonic sort + wave-shuffle scans ----------------
__global__ __launch_bounds__(1024) void k_sort(const float* __restrict__ e2,
                                               float* __restrict__ e2s,
                                               int* __restrict__ sidx,
                                               float* __restrict__ z1,
                                               float* __restrict__ z2) {
    __shared__ float vals[NN];
    __shared__ int   idxs[NN];
    __shared__ float2 wtot[16];
    __shared__ float2 woff[16];
    const int b = blockIdx.x;
    const int t = threadIdx.x;

    for (int i = t; i < NN; i += 1024) { vals[i] = e2[b * NN + i]; idxs[i] = i; }
    __syncthreads();

    for (int size = 2; size <= NN; size <<= 1) {
        for (int stride = size >> 1; stride > 0; stride >>= 1) {
            int i = ((t & ~(stride - 1)) << 1) | (t & (stride - 1));
            int j = i | stride;
            bool up = ((i & size) == 0);
            float vi = vals[i], vj = vals[j];
            bool sw = up ? (vi > vj) : (vi < vj);
            if (sw) {
                vals[i] = vj; vals[j] = vi;
                int ti = idxs[i]; idxs[i] = idxs[j]; idxs[j] = ti;
            }
            __syncthreads();
        }
    }

    for (int i = t; i < NN; i += 1024) {
        e2s[b * NN + i] = vals[i];
        sidx[b * NN + i] = idxs[i];
    }

    // dual inclusive scan (exp(v), exp(.2v)) via wave shuffles
    float v0 = vals[2 * t], v1 = vals[2 * t + 1];
    float x0a = expf(v0), x0b = expf(ALPHA * v0);
    float x1a = expf(v1), x1b = expf(ALPHA * v1);
    float pa = x0a + x1a, pb = x0b + x1b;
    float sa = pa, sb = pb;
    const int lane = t & 63, wid = t >> 6;
#pragma unroll
    for (int off = 1; off < 64; off <<= 1) {
        float ya = __shfl_up(sa, off, 64);
        float yb = __shfl_up(sb, off, 64);
        if (lane >= off) { sa += ya; sb += yb; }
    }
    if (lane == 63) wtot[wid] = make_float2(sa, sb);
    __syncthreads();
    if (t == 0) {
        float ra = 0.f, rb = 0.f;
        for (int w2 = 0; w2 < 16; ++w2) {
            float2 tt = wtot[w2];
            woff[w2] = make_float2(ra, rb);
            ra += tt.x; rb += tt.y;
        }
    }
    __syncthreads();
    float2 o = woff[wid];
    float pre_a = o.x + sa - pa, pre_b = o.y + sb - pb;
    float* Z1 = z1 + b * (NN + 1);
    float* Z2 = z2 + b * (NN + 1);
    if (t == 0) { Z1[0] = 0.f; Z2[0] = 0.f; }
    Z1[2 * t + 1] = pre_a + x0a;  Z2[2 * t + 1] = pre_b + x0b;
    Z1[2 * t + 2] = pre_a + pa;   Z2[2 * t + 2] = pre_b + pb;
}

// ---------------- K_chunks: per-chunk weighted text sums (C-space) ----------------
__global__ __launch_bounds__(128) void k_chunks(const void* __restrict__ text,
                                                const float* __restrict__ e2s,
                                                const int* __restrict__ sidx,
                                                float* __restrict__ G1,
                                                float* __restrict__ G2,
                                                const int* __restrict__ flag) {
    const int f32 = *flag;
    const int b = blockIdx.x / CHN, ch = blockIdx.x % CHN;
    const int c = threadIdx.x;
    float r1 = 0.f, r2 = 0.f;
    const int k0 = ch * CLEN;
#pragma unroll
    for (int kk = 0; kk < CLEN; ++kk) {
        int k = k0 + kk;
        float v = e2s[b * NN + k];
        int j = sidx[b * NN + k];
        float x = ld1(text, (b * NN + j) * CC + c, f32);
        r1 += expf(v) * x;
        r2 += expf(ALPHA * v) * x;
    }
    G1[(b * (CHN + 1) + ch) * CC + c] = r1;
    G2[(b * (CHN + 1) + ch) * CC + c] = r2;
}

// ---------------- K_mid: chunk scan (blocks 0..3) + rowinfo (blocks 4..67) ----------
__global__ __launch_bounds__(256) void k_mid(float* __restrict__ G1,
                                             float* __restrict__ G2,
                                             const float* __restrict__ e1,
                                             const float* __restrict__ e2s,
                                             const float* __restrict__ z1,
                                             const float* __restrict__ z2,
                                             float4* __restrict__ rowinfo) {
    if (blockIdx.x < 4) {
        const int tid = blockIdx.x * 256 + threadIdx.x;   // 0..B*C-1
        const int b = tid / CC, c = tid % CC;
        float* P1 = G1 + (size_t)(b * (CHN + 1)) * CC + c;
        float* P2 = G2 + (size_t)(b * (CHN + 1)) * CC + c;
        float r1 = 0.f, r2 = 0.f;
        for (int ch = 0; ch < CHN; ++ch) {
            float t1 = P1[ch * CC], t2 = P2[ch * CC];
            P1[ch * CC] = r1; r1 += t1;
            P2[ch * CC] = r2; r2 += t2;
        }
        P1[CHN * CC] = r1;   // totals
        P2[CHN * CC] = r2;
    } else {
        const int row = (blockIdx.x - 4) * 256 + threadIdx.x;  // 0..16383
        const int b = row >> 11;
        float ev = e1[row];
        float w1 = expf(ev), w2 = expf(ALPHA * ev);
        float thr = -ev;
        const float* e2sb = e2s + b * NN;
        int lo = 0, hi = NN;
        while (lo < hi) {                  // k = #{ j : e2s[j] <= thr }
            int mid = (lo + hi) >> 1;
            if (e2sb[mid] <= thr) lo = mid + 1; else hi = mid;
        }
        float den = w1 * (z1[b * (NN + 1) + NN] - z1[b * (NN + 1) + lo])
                  + w2 * z2[b * (NN + 1) + lo];
        den = fmaxf(den, 1e-30f);
        rowinfo[row] = make_float4(__int_as_float(lo), w1, w2, 1.f / den);
    }
}

// ---------------- K_ps: element-granular prefix arrays PS1/PS2 ----------------
__global__ __launch_bounds__(128) void k_ps(const void* __restrict__ text,
                                            const float* __restrict__ e2s,
                                            const int* __restrict__ sidx,
                                            const float* __restrict__ G1,
                                            const float* __restrict__ G2,
                                            float* __restrict__ PS1,
                                            float* __restrict__ PS2,
                                            const int* __restrict__ flag) {
    const int f32 = *flag;
    const int b = blockIdx.x / CHN, ch = blockIdx.x % CHN;
    const int c = threadIdx.x;
    float r1 = G1[(b * (CHN + 1) + ch) * CC + c];   // exclusive prefix at chunk start
    float r2 = G2[(b * (CHN + 1) + ch) * CC + c];
    const int k0 = ch * CLEN;
#pragma unroll
    for (int kk = 0; kk < CLEN; ++kk) {
        int k = k0 + kk;
        PS1[(size_t)(b * (NN + 1) + k) * CC + c] = r1;
        PS2[(size_t)(b * (NN + 1) + k) * CC + c] = r2;
        float v = e2s[b * NN + k];
        int j = sidx[b * NN + k];
        float x = ld1(text, (b * NN + j) * CC + c, f32);
        r1 += expf(v) * x;
        r2 += expf(ALPHA * v) * x;
    }
    if (ch == CHN - 1) {
        PS1[(size_t)(b * (NN + 1) + NN) * CC + c] = r1;
        PS2[(size_t)(b * (NN + 1) + NN) * CC + c] = r2;
    }
}

// ---------------- K_out: combine (phase 1) + MFMA @W (phase 2) + elu store -------
__global__ __launch_bounds__(256) void k_out(const void* __restrict__ text,
                                             const ushort* __restrict__ WT,
                                             const float* __restrict__ G1,
                                             const float* __restrict__ G2,
                                             const float* __restrict__ PS1,
                                             const float* __restrict__ PS2,
                                             const float4* __restrict__ rowinfo,
                                             const float* __restrict__ e2s,
                                             const int* __restrict__ sidx,
                                             void* __restrict__ out,
                                             const int* __restrict__ flag,
                                             int use_ps) {
    __shared__ ushort WTl[FF * WTPAD];     // 34816 B, bf16 W^T padded
    __shared__ ushort ul[ROWS * WTPAD];    // 4352 B, bf16 u-tile padded
    __shared__ float4 ri[ROWS];
    const int f32 = *flag;
    const int t = threadIdx.x;
    const int b = blockIdx.x / (NN / ROWS);
    const int r0 = (blockIdx.x % (NN / ROWS)) * ROWS;

    // stage W^T: 2048 uint4 coalesced
    {
        const uint4* src = (const uint4*)WT;
#pragma unroll
        for (int i = 0; i < 8; ++i) {
            int idx = i * 256 + t;
            uint4 v = src[idx];
            int f = idx >> 4, cb = idx & 15;
            *(uint4*)&WTl[f * WTPAD + cb * 8] = v;
        }
    }
    if (t < ROWS) ri[t] = rowinfo[b * NN + r0 + t];
    __syncthreads();

    // phase 1: u[rr][c] = (w1*(S1-P1) + w2*P2)*inv + alpha*text  -> bf16 in LDS
    {
        const int c = t & 127;
        const int g = t >> 7;                 // 0..1 -> rows g*8..g*8+7
        if (use_ps) {
            const float* B1 = PS1 + (size_t)(b * (NN + 1)) * CC + c;
            const float* B2 = PS2 + (size_t)(b * (NN + 1)) * CC + c;
            const float S1 = B1[(size_t)NN * CC];
#pragma unroll
            for (int q = 0; q < 8; ++q) {
                const int rr = g * 8 + q;
                float4 info = ri[rr];
                const int k = __float_as_int(info.x);
                float P1 = B1[(size_t)k * CC];
                float P2 = B2[(size_t)k * CC];
                float tc = ld1(text, (b * NN + r0 + rr) * CC + c, f32);
                float u = (info.y * (S1 - P1) + info.z * P2) * info.w + ALPHA * tc;
                bf16 ub = __float2bfloat16(u);
                ul[rr * WTPAD + c] = *(const ushort*)&ub;
            }
        } else {
            const float S1 = G1[(b * (CHN + 1) + CHN) * CC + c];
            const float* e2sb = e2s + b * NN;
            const int* sb = sidx + b * NN;
#pragma unroll 1
            for (int q = 0; q < 8; ++q) {
                const int rr = g * 8 + q;
                float4 info = ri[rr];
                const int k = __float_as_int(info.x);
                const int c0 = k >> CSH;
                float P1 = G1[(b * (CHN + 1) + c0) * CC + c];
                float P2 = G2[(b * (CHN + 1) + c0) * CC + c];
#pragma unroll 1
                for (int t2 = c0 << CSH; t2 < k; ++t2) {
                    float v = e2sb[t2];
                    int j = sb[t2];
                    float x = ld1(text, (b * NN + j) * CC + c, f32);
                    P1 += expf(v) * x;
                    P2 += expf(ALPHA * v) * x;
                }
                float tc = ld1(text, (b * NN + r0 + rr) * CC + c, f32);
                float u = (info.y * (S1 - P1) + info.z * P2) * info.w + ALPHA * tc;
                bf16 ub = __float2bfloat16(u);
                ul[rr * WTPAD + c] = *(const ushort*)&ub;
            }
        }
    }
    __syncthreads();

    // phase 2: out[16 x 128] = elu(u @ W) via MFMA 16x16x32 bf16
    {
        const int wv = t >> 6;
        const int lane = t & 63;
        const int m = lane & 15;
        const int quad = lane >> 4;
        f32x4 acc0 = {0.f, 0.f, 0.f, 0.f};
        f32x4 acc1 = {0.f, 0.f, 0.f, 0.f};
        const int f0 = (wv * 2 + 0) * 16 + m;
        const int f1 = (wv * 2 + 1) * 16 + m;
#pragma unroll
        for (int kt = 0; kt < 4; ++kt) {
            const int ko = kt * 32 + quad * 8;
            short8 afrag = *(const short8*)&ul[m * WTPAD + ko];
            short8 bf0 = *(const short8*)&WTl[f0 * WTPAD + ko];
            short8 bf1 = *(const short8*)&WTl[f1 * WTPAD + ko];
            acc0 = __builtin_amdgcn_mfma_f32_16x16x32_bf16(afrag, bf0, acc0, 0, 0, 0);
            acc1 = __builtin_amdgcn_mfma_f32_16x16x32_bf16(afrag, bf1, acc1, 0, 0, 0);
        }
        // C/D: col = lane&15 (f within tile), row = quad*4+reg (u-row)
#pragma unroll
        for (int ft = 0; ft < 2; ++ft) {
            f32x4 acc = ft ? acc1 : acc0;
            const int f = (wv * 2 + ft) * 16 + m;
#pragma unroll
            for (int reg = 0; reg < 4; ++reg) {
                const int urow = quad * 4 + reg;
                float x = acc[reg];
                float y = x > 0.f ? x : expm1f(x);
                const int orow = b * NN + r0 + urow;
                if (f32) ((float*)out)[orow * FF + f] = y;
                else     ((bf16*)out)[orow * FF + f] = __float2bfloat16(y);
            }
        }
    }
}

extern "C" void kernel_launch(void* const* d_in, const int* in_sizes, int n_in,
                              void* d_out, int out_size, void* d_ws, size_t ws_size,
                              hipStream_t stream) {
    const void* text = d_in[0];
    const void* Wp   = (n_in >= 4) ? d_in[2] : d_in[1];
    const void* ap   = (n_in >= 4) ? d_in[3] : d_in[2];
    for (int i = 0; i < n_in; ++i) {
        int s = in_sizes[i];
        if (s == BB * NN * CC)      text = d_in[i];
        else if (s == CC * FF)      Wp = d_in[i];
        else if (s == 2 * FF)       ap = d_in[i];
    }

    float* w = (float*)d_ws;
    size_t off = 0;
    int*    flagp  = (int*)(w + off);      off += 16;
    float*  wa1    = w + off;              off += 128;
    float*  wa2    = w + off;              off += 128;
    ushort* WT     = (ushort*)(w + off);   off += 8192;            // 16K bf16
    float*  e1     = w + off;              off += BB * NN;
    float*  e2     = w + off;              off += BB * NN;
    float*  e2s    = w + off;              off += BB * NN;
    int*    sidx   = (int*)(w + off);      off += BB * NN;
    float*  z1     = w + off;              off += BB * (NN + 1);
    float*  z2     = w + off;              off += BB * (NN + 1);
    float4* rowinfo= (float4*)(w + ((off + 3) & ~(size_t)3));
    off = ((off + 3) & ~(size_t)3) + 4 * (size_t)BB * NN;
    float*  G1     = w + off;              off += (size_t)BB * (CHN + 1) * CC;
    float*  G2     = w + off;              off += (size_t)BB * (CHN + 1) * CC;
    size_t base_need = off * 4;
    float*  PS1    = w + off;              // element-granular prefixes (big)
    float*  PS2    = PS1 + (size_t)BB * (NN + 1) * CC;
    size_t ps_need = base_need + 2 * (size_t)BB * (NN + 1) * CC * 4;
    const int use_ps = (ws_size >= ps_need) ? 1 : 0;   // needs ~21 MB; ws is ~512 MB

    k_prep<<<9, 256, 0, stream>>>(text, Wp, ap, flagp, wa1, wa2, WT);
    k_e<<<BB * NN / 4, 256, 0, stream>>>(text, wa1, wa2, e1, e2, flagp);
    k_sort<<<BB, 1024, 0, stream>>>(e2, e2s, sidx, z1, z2);
    k_chunks<<<BB * CHN, 128, 0, stream>>>(text, e2s, sidx, G1, G2, flagp);
    k_mid<<<4 + BB * NN / 256, 256, 0, stream>>>(G1, G2, e1, e2s, z1, z2, rowinfo);
    if (use_ps)
        k_ps<<<BB * CHN, 128, 0, stream>>>(text, e2s, sidx, G1, G2, PS1, PS2, flagp);
    k_out<<<BB * NN / ROWS, 256, 0, stream>>>(text, WT, G1, G2, PS1, PS2, rowinfo,
                                              e2s, sidx, d_out, flagp, use_ps);
}

// Round 6
// 240.753 us; speedup vs baseline: 1.7104x; 1.0136x over previous
//
#include <hip/hip_runtime.h>
#include <hip/hip_bf16.h>

#define BB 8
#define NN 2048
#define CC 128
#define FF 128
#define ALPHA 0.2f
#define ROWS 16        // rows per k_out block
#define WTPAD 136      // padded LDS row stride in ushorts (272 B = 17*16B: 2-way bank alias only)
#define CHN 256        // chunks per batch
#define CLEN 8         // NN/CHN
#define CSH 3          // log2(CLEN)

typedef __hip_bfloat16 bf16;
typedef __attribute__((ext_vector_type(8))) short short8;   // 8 bf16 MFMA operand
typedef __attribute__((ext_vector_type(4))) float f32x4;    // MFMA accumulator
typedef unsigned long long u64;

// ---------------- dtype helpers ----------------
__device__ __forceinline__ float ld1(const void* p, int i, int f32) {
    if (f32) return ((const float*)p)[i];
    return __bfloat162float(((const bf16*)p)[i]);
}
__device__ __forceinline__ float2 ld2(const void* p, int pair, int f32) {
    if (f32) return ((const float2*)p)[pair];
    __hip_bfloat162 v = ((const __hip_bfloat162*)p)[pair];
    return make_float2(__bfloat162float(v.x), __bfloat162float(v.y));
}
__device__ __forceinline__ u64 shfl_xor_u64(u64 v, int mask) {
    int lo = (int)(unsigned)(v & 0xFFFFFFFFull);
    int hi = (int)(unsigned)(v >> 32);
    lo = __shfl_xor(lo, mask, 64);
    hi = __shfl_xor(hi, mask, 64);
    return ((u64)(unsigned)hi << 32) | (unsigned)lo;
}

// ---------------- K_prep: flag + wa + WT(bf16, f-major) ----------------
__global__ __launch_bounds__(256) void k_prep(const void* __restrict__ text,
                                              const void* __restrict__ W,
                                              const void* __restrict__ a,
                                              int* __restrict__ flag,
                                              float* __restrict__ wa1,
                                              float* __restrict__ wa2,
                                              ushort* __restrict__ WT) {
    __shared__ int cnt;
    __shared__ float aL[2 * FF];
    const int t = threadIdx.x;
    if (t == 0) cnt = 0;
    __syncthreads();
    // dtype probe: fp32 low-half words decode as huge bf16 values
    const ushort2* p = (const ushort2*)text;
    int local = 0;
    for (int i = t; i < 1024; i += 256) {
        ushort2 v = p[i];
        float f = __uint_as_float(((unsigned)v.x) << 16);
        if (!(fabsf(f) <= 100.f)) local++;
    }
    atomicAdd(&cnt, local);
    __syncthreads();
    const int f32 = (cnt >= 64) ? 1 : 0;

    if (blockIdx.x == 0) {
        if (t == 0) flag[0] = f32;
        aL[t] = ld1(a, t, f32);          // t < 256 = 2F
        __syncthreads();
        if (t < CC) {
            float s1 = 0.f, s2 = 0.f;
            for (int f = 0; f < FF; f += 4) {
                float w0 = ld1(W, t * FF + f, f32);
                float w1 = ld1(W, t * FF + f + 1, f32);
                float w2 = ld1(W, t * FF + f + 2, f32);
                float w3 = ld1(W, t * FF + f + 3, f32);
                s1 += w0 * aL[f] + w1 * aL[f + 1] + w2 * aL[f + 2] + w3 * aL[f + 3];
                s2 += w0 * aL[FF + f] + w1 * aL[FF + f + 1] + w2 * aL[FF + f + 2] + w3 * aL[FF + f + 3];
            }
            wa1[t] = s1; wa2[t] = s2;
        }
    } else {
        // WT[f*CC+cc] = bf16(W[cc*FF+f])
        const int base = (blockIdx.x - 1) * 2048;
        for (int i = 0; i < 8; ++i) {
            int idx = base + i * 256 + t;          // idx = cc*FF + f
            int cc = idx >> 7, f = idx & 127;
            float v = ld1(W, idx, f32);
            bf16 b = __float2bfloat16(v);
            WT[f * CC + cc] = *(const ushort*)&b;
        }
    }
}

// ---------------- K_e: e1/e2 per row (wave per row) ----------------
__global__ __launch_bounds__(256) void k_e(const void* __restrict__ text,
                                           const float* __restrict__ wa1,
                                           const float* __restrict__ wa2,
                                           float* __restrict__ e1,
                                           float* __restrict__ e2,
                                           const int* __restrict__ flag) {
    const int f32 = *flag;
    const int wave = threadIdx.x >> 6;
    const int lane = threadIdx.x & 63;
    const int row = blockIdx.x * 4 + wave;
    float2 tv = ld2(text, row * (CC / 2) + lane, f32);
    float s1 = tv.x * wa1[2 * lane] + tv.y * wa1[2 * lane + 1];
    float s2 = tv.x * wa2[2 * lane] + tv.y * wa2[2 * lane + 1];
#pragma unroll
    for (int off = 32; off > 0; off >>= 1) {
        s1 += __shfl_down(s1, off, 64);
        s2 += __shfl_down(s2, off, 64);
    }
    if (lane == 0) { e1[row] = s1; e2[row] = s2; }
}

// ---------------- K_sort: register bitonic (shfl) + wave-shuffle scans ----------------
// Packed key: (order-preserving uint32 of float) << 32 | original index. Unique keys
// -> deterministic. Thread t owns elements 2t, 2t+1. Strides 2..64 via shfl_xor
// (no barrier); strides >=128 via LDS (10 stages); stride 1 in-thread.
__global__ __launch_bounds__(1024) void k_sort(const float* __restrict__ e2,
                                               float* __restrict__ e2s,
                                               int* __restrict__ sidx,
                                               float* __restrict__ z1,
                                               float* __restrict__ z2) {
    __shared__ u64 lk[NN];                 // 16 KB
    __shared__ float2 wtot[16];
    __shared__ float2 woff[16];
    const int b = blockIdx.x;
    const int t = threadIdx.x;

    float f0 = e2[b * NN + 2 * t], f1 = e2[b * NN + 2 * t + 1];
    unsigned m0 = __float_as_uint(f0); m0 = (m0 & 0x80000000u) ? ~m0 : (m0 | 0x80000000u);
    unsigned m1 = __float_as_uint(f1); m1 = (m1 & 0x80000000u) ? ~m1 : (m1 | 0x80000000u);
    u64 s0 = ((u64)m0 << 32) | (unsigned)(2 * t);
    u64 s1 = ((u64)m1 << 32) | (unsigned)(2 * t + 1);

    for (int size = 2; size <= NN; size <<= 1) {
        const bool up = (((2 * t) & size) == 0);
        for (int stride = size >> 1; stride >= 1; stride >>= 1) {
            if (stride == 1) {
                u64 mn = s0 < s1 ? s0 : s1;
                u64 mx = s0 < s1 ? s1 : s0;
                s0 = up ? mn : mx;
                s1 = up ? mx : mn;
            } else if (stride <= 64) {
                const int m = stride >> 1;       // thread xor-mask, <= 32: in-wave
                u64 p0 = shfl_xor_u64(s0, m);
                u64 p1 = shfl_xor_u64(s1, m);
                const bool keepmin = (((t & m) == 0) == up);
                s0 = keepmin ? (s0 < p0 ? s0 : p0) : (s0 < p0 ? p0 : s0);
                s1 = keepmin ? (s1 < p1 ? s1 : p1) : (s1 < p1 ? p1 : s1);
            } else {
                lk[2 * t] = s0; lk[2 * t + 1] = s1;
                __syncthreads();
                u64 p0 = lk[(2 * t) ^ stride];
                u64 p1 = lk[(2 * t + 1) ^ stride];
                const bool keepmin = ((((2 * t) & stride) == 0) == up);
                s0 = keepmin ? (s0 < p0 ? s0 : p0) : (s0 < p0 ? p0 : s0);
                s1 = keepmin ? (s1 < p1 ? s1 : p1) : (s1 < p1 ? p1 : s1);
                __syncthreads();
            }
        }
    }

    // unpack
    unsigned k0 = (unsigned)(s0 >> 32), k1 = (unsigned)(s1 >> 32);
    float v0 = __uint_as_float((k0 & 0x80000000u) ? (k0 ^ 0x80000000u) : ~k0);
    float v1 = __uint_as_float((k1 & 0x80000000u) ? (k1 ^ 0x80000000u) : ~k1);
    e2s[b * NN + 2 * t] = v0;
    e2s[b * NN + 2 * t + 1] = v1;
    sidx[b * NN + 2 * t] = (int)(unsigned)(s0 & 0xFFFFFFFFull);
    sidx[b * NN + 2 * t + 1] = (int)(unsigned)(s1 & 0xFFFFFFFFull);

    // dual inclusive scan (exp(v), exp(.2v)) via wave shuffles -> exclusive z arrays
    float x0a = expf(v0), x0b = expf(ALPHA * v0);
    float x1a = expf(v1), x1b = expf(ALPHA * v1);
    float pa = x0a + x1a, pb = x0b + x1b;
    float sa = pa, sb = pb;
    const int lane = t & 63, wid = t >> 6;
#pragma unroll
    for (int off = 1; off < 64; off <<= 1) {
        float ya = __shfl_up(sa, off, 64);
        float yb = __shfl_up(sb, off, 64);
        if (lane >= off) { sa += ya; sb += yb; }
    }
    if (lane == 63) wtot[wid] = make_float2(sa, sb);
    __syncthreads();
    if (t == 0) {
        float ra = 0.f, rb = 0.f;
        for (int w2 = 0; w2 < 16; ++w2) {
            float2 tt = wtot[w2];
            woff[w2] = make_float2(ra, rb);
            ra += tt.x; rb += tt.y;
        }
    }
    __syncthreads();
    float2 o = woff[wid];
    float pre_a = o.x + sa - pa, pre_b = o.y + sb - pb;
    float* Z1 = z1 + b * (NN + 1);
    float* Z2 = z2 + b * (NN + 1);
    if (t == 0) { Z1[0] = 0.f; Z2[0] = 0.f; }
    Z1[2 * t + 1] = pre_a + x0a;  Z2[2 * t + 1] = pre_b + x0b;
    Z1[2 * t + 2] = pre_a + pa;   Z2[2 * t + 2] = pre_b + pb;
}

// ---------------- K_ps: local prefix arrays + chunk totals (merged k_chunks) ------
__global__ __launch_bounds__(128) void k_ps(const void* __restrict__ text,
                                            const float* __restrict__ e2s,
                                            const int* __restrict__ sidx,
                                            float* __restrict__ PS1,
                                            float* __restrict__ PS2,
                                            float* __restrict__ T1,
                                            float* __restrict__ T2,
                                            const int* __restrict__ flag) {
    const int f32 = *flag;
    const int b = blockIdx.x / CHN, ch = blockIdx.x % CHN;
    const int c = threadIdx.x;
    float r1 = 0.f, r2 = 0.f;
    const int k0 = ch * CLEN;
#pragma unroll
    for (int kk = 0; kk < CLEN; ++kk) {
        int k = k0 + kk;
        PS1[(size_t)(b * NN + k) * CC + c] = r1;   // prefix LOCAL to chunk
        PS2[(size_t)(b * NN + k) * CC + c] = r2;
        float v = e2s[b * NN + k];
        int j = sidx[b * NN + k];
        float x = ld1(text, (b * NN + j) * CC + c, f32);
        r1 += expf(v) * x;
        r2 += expf(ALPHA * v) * x;
    }
    T1[(b * (CHN + 1) + ch) * CC + c] = r1;        // chunk totals
    T2[(b * (CHN + 1) + ch) * CC + c] = r2;
}

// ---------------- K_scanT: exclusive scan of chunk totals -> chunk bases ----------
__global__ __launch_bounds__(256) void k_scanT(float* __restrict__ T1,
                                               float* __restrict__ T2) {
    const int tid = blockIdx.x * 256 + threadIdx.x;   // 0..B*C-1
    const int b = tid / CC, c = tid % CC;
    float* P1 = T1 + (size_t)(b * (CHN + 1)) * CC + c;
    float* P2 = T2 + (size_t)(b * (CHN + 1)) * CC + c;
    float r1 = 0.f, r2 = 0.f;
    for (int ch = 0; ch < CHN; ch += 8) {
        float t1[8], t2[8];
#pragma unroll
        for (int u = 0; u < 8; ++u) { t1[u] = P1[(ch + u) * CC]; t2[u] = P2[(ch + u) * CC]; }
#pragma unroll
        for (int u = 0; u < 8; ++u) {
            P1[(ch + u) * CC] = r1; r1 += t1[u];
            P2[(ch + u) * CC] = r2; r2 += t2[u];
        }
    }
    P1[CHN * CC] = r1;   // totals at slot CHN
    P2[CHN * CC] = r2;
}

// ---------------- K_out: search + combine + MFMA @W + elu store -------------------
__global__ __launch_bounds__(256) void k_out(const void* __restrict__ text,
                                             const ushort* __restrict__ WT,
                                             const float* __restrict__ T1,
                                             const float* __restrict__ T2,
                                             const float* __restrict__ PS1,
                                             const float* __restrict__ PS2,
                                             const float* __restrict__ e1,
                                             const float* __restrict__ e2s,
                                             const float* __restrict__ z1,
                                             const float* __restrict__ z2,
                                             void* __restrict__ out,
                                             const int* __restrict__ flag) {
    __shared__ ushort WTl[FF * WTPAD];     // 34816 B, bf16 W^T padded
    __shared__ ushort ul[ROWS * WTPAD];    // 4352 B, bf16 u-tile padded
    __shared__ float4 ri[ROWS];
    const int f32 = *flag;
    const int t = threadIdx.x;
    const int b = blockIdx.x / (NN / ROWS);
    const int r0 = (blockIdx.x % (NN / ROWS)) * ROWS;

    // stage W^T: 2048 uint4 coalesced (L2-resident, 32 KB unique)
    {
        const uint4* src = (const uint4*)WT;
#pragma unroll
        for (int i = 0; i < 8; ++i) {
            int idx = i * 256 + t;
            uint4 v = src[idx];
            int f = idx >> 4, cb = idx & 15;
            *(uint4*)&WTl[f * WTPAD + cb * 8] = v;
        }
    }
    // 16 parallel binary searches (overlap WT staging latency)
    if (t < ROWS) {
        const int row = b * NN + r0 + t;
        float ev = e1[row];
        float w1 = expf(ev), w2 = expf(ALPHA * ev);
        float thr = -ev;
        const float* e2sb = e2s + b * NN;
        int lo = 0, hi = NN;
        while (lo < hi) {                  // k = #{ j : e2s[j] <= thr }
            int mid = (lo + hi) >> 1;
            if (e2sb[mid] <= thr) lo = mid + 1; else hi = mid;
        }
        float den = w1 * (z1[b * (NN + 1) + NN] - z1[b * (NN + 1) + lo])
                  + w2 * z2[b * (NN + 1) + lo];
        den = fmaxf(den, 1e-30f);
        ri[t] = make_float4(__int_as_float(lo), w1, w2, 1.f / den);
    }
    __syncthreads();

    // phase 1: u[rr][c] = (w1*(S1-P1) + w2*P2)*inv + alpha*text  -> bf16 in LDS
    {
        const int c = t & 127;
        const int g = t >> 7;                 // 0..1 -> rows g*8..g*8+7
        const float* CB1 = T1 + (size_t)(b * (CHN + 1)) * CC + c;
        const float* CB2 = T2 + (size_t)(b * (CHN + 1)) * CC + c;
        const float* B1 = PS1 + (size_t)(b * NN) * CC + c;
        const float* B2 = PS2 + (size_t)(b * NN) * CC + c;
        const float S1 = CB1[CHN * CC];
#pragma unroll
        for (int q = 0; q < 8; ++q) {
            const int rr = g * 8 + q;
            float4 info = ri[rr];
            const int k = __float_as_int(info.x);
            const int c0 = k >> CSH;
            float P1 = CB1[c0 * CC];
            float P2 = CB2[c0 * CC];
            if (k < NN) {                     // local part (0 at chunk starts; k==NN OOB-guard)
                P1 += B1[(size_t)k * CC];
                P2 += B2[(size_t)k * CC];
            }
            float tc = ld1(text, (b * NN + r0 + rr) * CC + c, f32);
            float u = (info.y * (S1 - P1) + info.z * P2) * info.w + ALPHA * tc;
            bf16 ub = __float2bfloat16(u);
            ul[rr * WTPAD + c] = *(const ushort*)&ub;
        }
    }
    __syncthreads();

    // phase 2: out[16 x 128] = elu(u @ W) via MFMA 16x16x32 bf16
    {
        const int wv = t >> 6;
        const int lane = t & 63;
        const int m = lane & 15;
        const int quad = lane >> 4;
        f32x4 acc0 = {0.f, 0.f, 0.f, 0.f};
        f32x4 acc1 = {0.f, 0.f, 0.f, 0.f};
        const int f0 = (wv * 2 + 0) * 16 + m;
        const int f1 = (wv * 2 + 1) * 16 + m;
#pragma unroll
        for (int kt = 0; kt < 4; ++kt) {
            const int ko = kt * 32 + quad * 8;
            short8 afrag = *(const short8*)&ul[m * WTPAD + ko];
            short8 bf0 = *(const short8*)&WTl[f0 * WTPAD + ko];
            short8 bf1 = *(const short8*)&WTl[f1 * WTPAD + ko];
            acc0 = __builtin_amdgcn_mfma_f32_16x16x32_bf16(afrag, bf0, acc0, 0, 0, 0);
            acc1 = __builtin_amdgcn_mfma_f32_16x16x32_bf16(afrag, bf1, acc1, 0, 0, 0);
        }
        // C/D: col = lane&15 (f within tile), row = quad*4+reg (u-row)
#pragma unroll
        for (int ft = 0; ft < 2; ++ft) {
            f32x4 acc = ft ? acc1 : acc0;
            const int f = (wv * 2 + ft) * 16 + m;
#pragma unroll
            for (int reg = 0; reg < 4; ++reg) {
                const int urow = quad * 4 + reg;
                float x = acc[reg];
                float y = x > 0.f ? x : expm1f(x);
                const int orow = b * NN + r0 + urow;
                if (f32) ((float*)out)[orow * FF + f] = y;
                else     ((bf16*)out)[orow * FF + f] = __float2bfloat16(y);
            }
        }
    }
}

extern "C" void kernel_launch(void* const* d_in, const int* in_sizes, int n_in,
                              void* d_out, int out_size, void* d_ws, size_t ws_size,
                              hipStream_t stream) {
    const void* text = d_in[0];
    const void* Wp   = (n_in >= 4) ? d_in[2] : d_in[1];
    const void* ap   = (n_in >= 4) ? d_in[3] : d_in[2];
    for (int i = 0; i < n_in; ++i) {
        int s = in_sizes[i];
        if (s == BB * NN * CC)      text = d_in[i];
        else if (s == CC * FF)      Wp = d_in[i];
        else if (s == 2 * FF)       ap = d_in[i];
    }

    float* w = (float*)d_ws;
    size_t off = 0;
    int*    flagp  = (int*)(w + off);      off += 16;
    float*  wa1    = w + off;              off += 128;
    float*  wa2    = w + off;              off += 128;
    ushort* WT     = (ushort*)(w + off);   off += 8192;            // 16K bf16
    float*  e1     = w + off;              off += BB * NN;
    float*  e2     = w + off;              off += BB * NN;
    float*  e2s    = w + off;              off += BB * NN;
    int*    sidx   = (int*)(w + off);      off += BB * NN;
    float*  z1     = w + off;              off += BB * (NN + 1);
    float*  z2     = w + off;              off += BB * (NN + 1);
    float*  T1     = w + off;              off += (size_t)BB * (CHN + 1) * CC;
    float*  T2     = w + off;              off += (size_t)BB * (CHN + 1) * CC;
    float*  PS1    = w + off;              off += (size_t)BB * NN * CC;
    float*  PS2    = w + off;              off += (size_t)BB * NN * CC;
    // total ~19.3 MB; ws is ~512 MB (measured via harness fill: 524288 KB)

    k_prep<<<9, 256, 0, stream>>>(text, Wp, ap, flagp, wa1, wa2, WT);
    k_e<<<BB * NN / 4, 256, 0, stream>>>(text, wa1, wa2, e1, e2, flagp);
    k_sort<<<BB, 1024, 0, stream>>>(e2, e2s, sidx, z1, z2);
    k_ps<<<BB * CHN, 128, 0, stream>>>(text, e2s, sidx, PS1, PS2, T1, T2, flagp);
    k_scanT<<<4, 256, 0, stream>>>(T1, T2);
    k_out<<<BB * NN / ROWS, 256, 0, stream>>>(text, WT, T1, T2, PS1, PS2,
                                              e1, e2s, z1, z2, d_out, flagp);
}